// Round 6
// baseline (4594.999 us; speedup 1.0000x reference)
//
#include <hip/hip_runtime.h>
#include <stdint.h>

#define HTABLE (1u << 19)
#define TMASK  (HTABLE - 1u)
#define TILE   64
#define KSTR   264   // hB row stride in bf16 elems (528 B: 16B-aligned, 2-way-free banks)
#define KE     40    // encB row stride in bf16 elems

typedef __attribute__((ext_vector_type(8))) short short8;
typedef __attribute__((ext_vector_type(4))) float floatx4;

__device__ __forceinline__ float relu_(float v) { return fmaxf(v, 0.f); }

__device__ __forceinline__ uint32_t f2bf(float f) {
    uint32_t u = __float_as_uint(f);
    return (u + 0x7FFFu + ((u >> 16) & 1u)) >> 16;
}
__device__ __forceinline__ float bf2f(uint32_t h) { return __uint_as_float(h << 16); }

// variable-index extract from a 16B quad: 3 cndmasks, no scratch
__device__ __forceinline__ uint32_t sel4(const uint4& v, uint32_t i) {
    uint32_t lo = (i & 1u) ? v.y : v.x;
    uint32_t hi = (i & 1u) ? v.w : v.z;
    return (i & 2u) ? hi : lo;
}

__device__ __constant__ uint32_t PRS[6] = {1u, 2654435761u, 805459861u, 3674653429u, 2097192037u, 1434869437u};
__device__ __constant__ float RESF[16]  = {16.f,20.f,25.f,32.f,40.f,50.f,64.f,80.f,101.f,128.f,161.f,203.f,256.f,322.f,406.f,512.f};
__device__ __constant__ float GRIDF[16] = {1.f/16.f,1.f/20.f,1.f/25.f,1.f/32.f,1.f/40.f,1.f/50.f,1.f/64.f,1.f/80.f,
                                           1.f/101.f,1.f/128.f,1.f/161.f,1.f/203.f,1.f/256.f,1.f/322.f,1.f/406.f,1.f/512.f};

// ---------------- binning kernels ----------------
__global__ void k_count(const int* __restrict__ lid, int n, int* __restrict__ cnt) {
    __shared__ int h4[4];
    int i = blockIdx.x * blockDim.x + threadIdx.x;
    if (threadIdx.x < 4) h4[threadIdx.x] = 0;
    __syncthreads();
    if (i < n) atomicAdd(&h4[lid[i] & 3], 1);
    __syncthreads();
    if (threadIdx.x < 4) atomicAdd(&cnt[threadIdx.x], h4[threadIdx.x]);
}

__global__ void k_offsets(const int* __restrict__ cnt, int* __restrict__ cursor) {
    if (threadIdx.x == 0 && blockIdx.x == 0) {
        int off = 0;
        for (int k = 0; k < 4; k++) {
            cursor[k] = off;
            off = (off + cnt[k] + 63) & ~63;
        }
    }
}

__global__ void k_scatter(const int* __restrict__ lid, int n, int* __restrict__ cursor, int* __restrict__ perm) {
    int i = blockIdx.x * blockDim.x + threadIdx.x;
    if (i >= n) return;
    int lane = threadIdx.x & 63;
    int c = lid[i] & 3;
    unsigned long long m0 = __ballot(c == 0), m1 = __ballot(c == 1);
    unsigned long long m2 = __ballot(c == 2), m3 = __ballot(c == 3);
    unsigned long long mc = (c == 0) ? m0 : (c == 1) ? m1 : (c == 2) ? m2 : m3;
    int rank = __popcll(mc & ((1ull << lane) - 1ull));
    int cntl = (lane == 0) ? __popcll(m0) : (lane == 1) ? __popcll(m1) : (lane == 2) ? __popcll(m2) : __popcll(m3);
    int basev = 0;
    if (lane < 4) basev = atomicAdd(&cursor[lane], cntl);
    int base = __shfl(basev, c, 64);
    perm[base + rank] = i;
}

// ---------------- pack embedding table to bf16: T[l][g] = (bf16(e.x), bf16(e.y)) ----------------
__global__ __launch_bounds__(256) void k_packtab(const float* __restrict__ emb, uint32_t* __restrict__ T) {
    const int i = blockIdx.x * 256 + threadIdx.x;
    float2 e = ((const float2*)emb)[i];
    T[i] = f2bf(e.x) | (f2bf(e.y) << 16);
}

// ---------------- weight prep: transpose + bf16 ----------------
// blocks 0..191: Wres [c][ib][k][n] fp32 -> Wrt [c][ib][n][k] bf16 (64x64 tiles)
// blocks 192..195: W0 [c][32][256] fp32 -> W0t [c][256][32] bf16
__global__ __launch_bounds__(256) void k_prep(const float* __restrict__ Wres, const float* __restrict__ W0,
                                              uint16_t* __restrict__ Wrt, uint16_t* __restrict__ W0t) {
    __shared__ float sm[64 * 65 > 32 * 257 ? 64 * 65 : 32 * 257];
    const int t = threadIdx.x;
    const int bid = blockIdx.x;
    if (bid < 192) {
        const int c = bid / 48, rem = bid % 48, ib = rem / 16, tile = rem % 16;
        const int n0 = (tile / 4) * 64, k0 = (tile % 4) * 64;
        const float* src = Wres + (size_t)(c * 3 + ib) * 65536;
        for (int i = 0; i < 16; i++) {
            int idx = t + 256 * i, r = idx >> 6, cc = idx & 63;
            sm[r * 65 + cc] = src[(size_t)(k0 + r) * 256 + n0 + cc];
        }
        __syncthreads();
        uint16_t* dst = Wrt + (size_t)(c * 3 + ib) * 65536;
        for (int i = 0; i < 16; i++) {
            int idx = t + 256 * i, rn = idx >> 6, ck = idx & 63;
            dst[(size_t)(n0 + rn) * 256 + k0 + ck] = (uint16_t)f2bf(sm[ck * 65 + rn]);
        }
    } else {
        const int c = bid - 192;
        for (int i = 0; i < 32; i++) {
            int idx = t + 256 * i, k = idx >> 8, n = idx & 255;
            sm[k * 257 + n] = W0[(size_t)c * 8192 + idx];
        }
        __syncthreads();
        for (int i = 0; i < 32; i++) {
            int idx = t + 256 * i, n = idx >> 5, k = idx & 31;
            W0t[(size_t)c * 8192 + idx] = (uint16_t)f2bf(sm[k * 257 + n]);
        }
    }
}

// ---------------- encode kernel: one level per block, level -> XCD pinned ----------------
// Dim0 prime = 1, so the dim0 vertex pair is {h, h^mask} with mask = bl0^(bl0+1).
// mask<=3 (75% of points): both entries in one 16B quad -> single dwordx4.
// mask in {7,15} (19%): second quad is in the SAME 64B line -> 2 reqs, 1 line fill.
// Only ~6% of points touch 2 lines per pair. Avg ~40 reqs / ~35 lines per point-level.
__global__ __launch_bounds__(256, 8) void k_encode(
    const float* __restrict__ x, const uint32_t* __restrict__ T,
    uint32_t* __restrict__ encP, int B)
{
    __shared__ float xs[256 * 6];
    const int t = threadIdx.x;
    const int NC8 = (B >> 8) << 3;
    const int pass = (blockIdx.x >= NC8) ? 1 : 0;
    const int rem  = blockIdx.x - pass * NC8;
    const int l    = (rem & 7) + (pass << 3);
    const int chunk = rem >> 3;
    const int pbase = chunk << 8;

    for (int idx = t; idx < 256 * 6; idx += 256) {
        float v = x[(size_t)pbase * 6 + idx];
        xs[idx] = fminf(fmaxf(v, 0.f), 1.f);
    }
    __syncthreads();

    const float res  = RESF[l];
    const float grid = GRIDF[l];
    float wv[6]; uint32_t ua[6], ub[6];
    #pragma unroll
    for (int d = 0; d < 6; d++) {
        float xv  = xs[t * 6 + d];
        float blf = floorf(xv * res);
        float w   = (xv - blf * grid) / (grid + 1e-6f);
        wv[d] = fminf(fmaxf(w, 0.f), 1.f);
        uint32_t uu = (uint32_t)(int)blf * PRS[d];
        ua[d] = uu; ub[d] = uu + PRS[d];
    }
    // v = (i<<4)|(j<<2)|k. Hash: dims (0,1)<-i, (2,3)<-j, (4,5)<-k (MSB-first).
    // Weights LSB-first: hash-dim0<->wv[5], dim1<->wv[4], dim2<->wv[3], dim3<->wv[2],
    // dim4<->wv[1], dim5<->wv[0] — faithful to the reference's bit-order mismatch.
    uint32_t HJ[4], HK[4]; float WJ[4], WK[4];
    #pragma unroll
    for (int q = 0; q < 4; q++) {
        const int b1 = (q >> 1) & 1, bb = q & 1;
        HJ[q] = (b1 ? ub[2] : ua[2]) ^ (bb ? ub[3] : ua[3]);
        HK[q] = (b1 ? ub[4] : ua[4]) ^ (bb ? ub[5] : ua[5]);
        WJ[q] = (bb ? wv[2] : 1.f - wv[2]) * (b1 ? wv[3] : 1.f - wv[3]);
        WK[q] = (bb ? wv[0] : 1.f - wv[0]) * (b1 ? wv[1] : 1.f - wv[1]);
    }
    const uint32_t D1[2] = {ua[1], ub[1]};
    const float   WD1[2] = {1.f - wv[4], wv[4]};
    const float w5a = 1.f - wv[5], w5b = wv[5];   // dim0 beta weights
    const uint32_t bl0  = ua[0];                  // prime = 1
    const uint32_t mask = bl0 ^ (bl0 + 1u);       // XOR delta of the dim0 vertex pair
    const bool narrow = (mask <= 3u);             // both vertices within one 16B quad
    const uint4* __restrict__ Tl4 = reinterpret_cast<const uint4*>(T + (size_t)l * HTABLE);

    float f0 = 0.f, f1 = 0.f;
    #pragma unroll
    for (int j1 = 0; j1 < 2; j1++) {
        #pragma unroll
        for (int j = 0; j < 4; j++) {
            const uint32_t Sj = D1[j1] ^ HJ[j];
            const float   wj = WD1[j1] * WJ[j];
            #pragma unroll
            for (int k = 0; k < 4; k++) {
                const uint32_t h  = (bl0 ^ Sj ^ HK[k]) & TMASK;
                const uint32_t h2 = h ^ mask;      // mask < 2^10, stays in-table
                const float wS = wj * WK[k];
                const uint4 La = Tl4[h >> 2];
                const uint32_t pa = sel4(La, h & 3u);            // E[bl0^S]
                uint32_t pb = sel4(La, h2 & 3u);                 // valid when narrow
                if (!narrow) {                                   // exec-masked wide path
                    const uint4 Lb = Tl4[h2 >> 2];
                    pb = sel4(Lb, h2 & 3u);
                }
                const float e0x = __uint_as_float(pa << 16),  e0y = __uint_as_float(pa & 0xFFFF0000u);
                const float e1x = __uint_as_float(pb << 16),  e1y = __uint_as_float(pb & 0xFFFF0000u);
                f0 = fmaf(wS, fmaf(w5a, e0x, w5b * e1x), f0);
                f1 = fmaf(wS, fmaf(w5a, e0y, w5b * e1y), f1);
            }
        }
    }
    encP[(size_t)l * B + pbase + t] = f2bf(f0) | (f2bf(f1) << 16);
}

// ---------------- MFMA MLP ----------------
// Per block: 64 class-uniform points. GEMMs computed as D[n=neuron][m=point] = W^T . H
// so C/D regs (4 consecutive neurons) are k-contiguous for the next layer's B operand.
// Wave wv owns neurons [wv*64, wv*64+64); fp32 residual carry lives in h_reg.
__global__ __launch_bounds__(256, 2) void k_mlp2(
    const int* __restrict__ lid, const uint32_t* __restrict__ encP,
    const uint16_t* __restrict__ W0t, const float* __restrict__ b0,
    const uint16_t* __restrict__ Wrt, const float* __restrict__ bres,
    const float* __restrict__ scales, const float* __restrict__ Wout, const float* __restrict__ bout,
    const int* __restrict__ perm, float* __restrict__ out, int B)
{
    __shared__ uint16_t hB[64 * KSTR];     // 33792 B  H as [point][k] bf16
    __shared__ uint16_t encB[64 * KE];     //  5120 B  enc as [point][k32] bf16
    __shared__ float    bs[256];           //  per-layer bias / Wout stage
    __shared__ float    outP[256];
    __shared__ int      permL[TILE];

    const int t  = threadIdx.x;
    const int lane = t & 63;
    const int wv = t >> 6;          // wave id: neuron slice
    const int mi = lane & 15;       // point within 16-col
    const int q  = lane >> 4;       // quad

    if (t < TILE) permL[t] = perm[(size_t)blockIdx.x * TILE + t];
    __syncthreads();
    const int g0 = permL[0];
    if (g0 < 0) return;
    const int c = lid[g0] & 3;

    // stage enc [point][k=2l..2l+1] and b0
    bs[t] = b0[c * 256 + t];
    for (int idx = t; idx < 16 * 64; idx += 256) {
        const int l = idx >> 6, pp = idx & 63;
        const int gi = permL[pp];
        ((uint32_t*)encB)[pp * (KE / 2) + l] = (gi >= 0) ? encP[(size_t)l * B + gi] : 0u;
    }
    __syncthreads();

    floatx4 acc[4][4];
    floatx4 h_reg[4][4];

    // ---- layer 0: D = W0^T(256x32) . enc(32x64)
    {
        #pragma unroll
        for (int mt = 0; mt < 4; mt++)
            #pragma unroll
            for (int nt = 0; nt < 4; nt++) acc[mt][nt] = (floatx4){0.f, 0.f, 0.f, 0.f};
        const short8* Wp = (const short8*)(W0t + (size_t)c * 8192);
        short8 A[4], Bf[4];
        #pragma unroll
        for (int mt = 0; mt < 4; mt++) A[mt] = Wp[(wv * 64 + mt * 16 + mi) * 4 + q];
        #pragma unroll
        for (int nt = 0; nt < 4; nt++) Bf[nt] = *(const short8*)&encB[(nt * 16 + mi) * KE + q * 8];
        #pragma unroll
        for (int mt = 0; mt < 4; mt++)
            #pragma unroll
            for (int nt = 0; nt < 4; nt++)
                acc[mt][nt] = __builtin_amdgcn_mfma_f32_16x16x32_bf16(A[mt], Bf[nt], acc[mt][nt], 0, 0, 0);
        // h = relu(u + b0); write bf16 to hB
        #pragma unroll
        for (int mt = 0; mt < 4; mt++) {
            const int nb = wv * 64 + mt * 16 + q * 4;
            #pragma unroll
            for (int nt = 0; nt < 4; nt++) {
                floatx4 u = acc[mt][nt], h;
                h[0] = relu_(u[0] + bs[nb + 0]); h[1] = relu_(u[1] + bs[nb + 1]);
                h[2] = relu_(u[2] + bs[nb + 2]); h[3] = relu_(u[3] + bs[nb + 3]);
                h_reg[mt][nt] = h;
                uint2 pk; pk.x = f2bf(h[0]) | (f2bf(h[1]) << 16); pk.y = f2bf(h[2]) | (f2bf(h[3]) << 16);
                *(uint2*)&hB[(nt * 16 + mi) * KSTR + nb] = pk;
            }
        }
    }
    __syncthreads();

    // ---- 3 scaled residual blocks
    #pragma unroll 1
    for (int ib = 0; ib < 3; ib++) {
        bs[t] = bres[(size_t)((c * 3 + ib) << 8) + t];   // read after the post-MFMA barrier
        const float s = scales[c * 3 + ib];
        #pragma unroll
        for (int mt = 0; mt < 4; mt++)
            #pragma unroll
            for (int nt = 0; nt < 4; nt++) acc[mt][nt] = (floatx4){0.f, 0.f, 0.f, 0.f};

        const short8* Wp = (const short8*)(Wrt + (size_t)(c * 3 + ib) * 65536);
        short8 Acur[4], Anext[4], Bf[4];
        #pragma unroll
        for (int mt = 0; mt < 4; mt++) Acur[mt] = Wp[(wv * 64 + mt * 16 + mi) * 32 + q];
        #pragma unroll 1
        for (int ks = 0; ks < 8; ks++) {
            #pragma unroll
            for (int nt = 0; nt < 4; nt++)
                Bf[nt] = *(const short8*)&hB[(nt * 16 + mi) * KSTR + ks * 32 + q * 8];
            if (ks < 7) {
                #pragma unroll
                for (int mt = 0; mt < 4; mt++)
                    Anext[mt] = Wp[(wv * 64 + mt * 16 + mi) * 32 + (ks + 1) * 4 + q];
            }
            #pragma unroll
            for (int mt = 0; mt < 4; mt++)
                #pragma unroll
                for (int nt = 0; nt < 4; nt++)
                    acc[mt][nt] = __builtin_amdgcn_mfma_f32_16x16x32_bf16(Acur[mt], Bf[nt], acc[mt][nt], 0, 0, 0);
            #pragma unroll
            for (int mt = 0; mt < 4; mt++) Acur[mt] = Anext[mt];
        }
        __syncthreads();   // hB reads done; bs staged
        #pragma unroll
        for (int mt = 0; mt < 4; mt++) {
            const int nb = wv * 64 + mt * 16 + q * 4;
            #pragma unroll
            for (int nt = 0; nt < 4; nt++) {
                floatx4 u = acc[mt][nt];
                floatx4 h = h_reg[mt][nt];
                h[0] = fmaf(s, relu_(u[0] + bs[nb + 0]), h[0]);
                h[1] = fmaf(s, relu_(u[1] + bs[nb + 1]), h[1]);
                h[2] = fmaf(s, relu_(u[2] + bs[nb + 2]), h[2]);
                h[3] = fmaf(s, relu_(u[3] + bs[nb + 3]), h[3]);
                h_reg[mt][nt] = h;
                if (ib < 2) {
                    uint2 pk; pk.x = f2bf(h[0]) | (f2bf(h[1]) << 16); pk.y = f2bf(h[2]) | (f2bf(h[3]) << 16);
                    *(uint2*)&hB[(nt * 16 + mi) * KSTR + nb] = pk;
                }
            }
        }
        if (ib < 2) __syncthreads();
    }

    // ---- output layer: out[p] = sum_n h[n][p] * Wout[n] + bout
    __syncthreads();
    bs[t] = Wout[c * 256 + t];
    __syncthreads();
    float po[4] = {0.f, 0.f, 0.f, 0.f};
    #pragma unroll
    for (int mt = 0; mt < 4; mt++) {
        const int nb = wv * 64 + mt * 16 + q * 4;
        const float w0v = bs[nb + 0], w1v = bs[nb + 1], w2v = bs[nb + 2], w3v = bs[nb + 3];
        #pragma unroll
        for (int nt = 0; nt < 4; nt++) {
            const floatx4 h = h_reg[mt][nt];
            po[nt] += h[0] * w0v + h[1] * w1v + h[2] * w2v + h[3] * w3v;
        }
    }
    #pragma unroll
    for (int nt = 0; nt < 4; nt++) {
        float v = po[nt];
        v += __shfl_xor(v, 16, 64);
        v += __shfl_xor(v, 32, 64);
        if (q == 0) outP[wv * 64 + nt * 16 + mi] = v;
    }
    __syncthreads();
    if (t < TILE) {
        float r = outP[t] + outP[64 + t] + outP[128 + t] + outP[192 + t] + bout[c];
        const int gi = permL[t];
        if (gi >= 0) out[gi] = r;
    }
}

extern "C" void kernel_launch(void* const* d_in, const int* in_sizes, int n_in,
                              void* d_out, int out_size, void* d_ws, size_t ws_size,
                              hipStream_t stream) {
    const float* x      = (const float*)d_in[0];
    const int*   lid    = (const int*)  d_in[1];
    const float* emb    = (const float*)d_in[2];
    const float* W0     = (const float*)d_in[3];
    const float* b0     = (const float*)d_in[4];
    const float* Wres   = (const float*)d_in[5];
    const float* bres   = (const float*)d_in[6];
    const float* scales = (const float*)d_in[7];
    const float* Wout   = (const float*)d_in[8];
    const float* bout   = (const float*)d_in[9];
    float* out = (float*)d_out;

    const int B = in_sizes[1];                          // 524288 points
    int* cnt    = (int*)d_ws;                           // [0..3]
    int* cursor = cnt + 4;                              // [4..7]
    int* perm   = cnt + 64;                             // +256 B, padded permutation (~2.1 MB)
    uint16_t* W0t = (uint16_t*)((char*)d_ws + 2228224); // +2.125 MB: [4][256][32] bf16 (64 KB)
    uint16_t* Wrt = (uint16_t*)((char*)d_ws + 2359296); // +2.25 MB: [4][3][256][256] bf16 (1.5 MB)
    uint32_t* encP = (uint32_t*)((char*)d_ws + (4u << 20));   // +4 MB: [16][B] packed bf16 pairs (32 MB)
    uint32_t* T    = (uint32_t*)((char*)d_ws + (36u << 20));  // +36 MB: bf16 pair table [16][2^19] (32 MB)
    const int nblk = B / TILE + 4;                      // 8196

    (void)hipMemsetAsync(d_ws, 0, 32, stream);
    (void)hipMemsetAsync(perm, 0xFF, (size_t)nblk * TILE * sizeof(int), stream);
    k_packtab<<<(16 * (int)HTABLE) / 256, 256, 0, stream>>>(emb, T);
    k_prep   <<<196, 256, 0, stream>>>(Wres, W0, Wrt, W0t);
    k_count  <<<B / 256, 256, 0, stream>>>(lid, B, cnt);
    k_offsets<<<1, 64, 0, stream>>>(cnt, cursor);
    k_scatter<<<B / 256, 256, 0, stream>>>(lid, B, cursor, perm);
    k_encode <<<(B / 256) * 16, 256, 0, stream>>>(x, T, encP, B);
    k_mlp2   <<<nblk, 256, 0, stream>>>(lid, encP, W0t, b0, Wrt, bres, scales, Wout, bout, perm, out, B);
}

// Round 7
// 2603.290 us; speedup vs baseline: 1.7651x; 1.7651x over previous
//
#include <hip/hip_runtime.h>
#include <stdint.h>

#define HTABLE (1u << 19)
#define TMASK  (HTABLE - 1u)
#define TILE   64
#define KSTR   264   // hB row stride in bf16 elems (528 B: 16B-aligned, 2-way-free banks)
#define KE     40    // encB row stride in bf16 elems

typedef __attribute__((ext_vector_type(8))) short short8;
typedef __attribute__((ext_vector_type(4))) float floatx4;

__device__ __forceinline__ float relu_(float v) { return fmaxf(v, 0.f); }

__device__ __forceinline__ uint32_t f2bf(float f) {
    uint32_t u = __float_as_uint(f);
    return (u + 0x7FFFu + ((u >> 16) & 1u)) >> 16;
}
__device__ __forceinline__ float bf2f(uint32_t h) { return __uint_as_float(h << 16); }

// variable-index extract from a 16B quad: 3 cndmasks, no scratch
__device__ __forceinline__ uint32_t sel4(const uint4& v, uint32_t i) {
    uint32_t lo = (i & 1u) ? v.y : v.x;
    uint32_t hi = (i & 1u) ? v.w : v.z;
    return (i & 2u) ? hi : lo;
}

__device__ __constant__ uint32_t PRS[6] = {1u, 2654435761u, 805459861u, 3674653429u, 2097192037u, 1434869437u};
__device__ __constant__ float RESF[16]  = {16.f,20.f,25.f,32.f,40.f,50.f,64.f,80.f,101.f,128.f,161.f,203.f,256.f,322.f,406.f,512.f};
__device__ __constant__ float GRIDF[16] = {1.f/16.f,1.f/20.f,1.f/25.f,1.f/32.f,1.f/40.f,1.f/50.f,1.f/64.f,1.f/80.f,
                                           1.f/101.f,1.f/128.f,1.f/161.f,1.f/203.f,1.f/256.f,1.f/322.f,1.f/406.f,1.f/512.f};

// ---------------- binning kernels ----------------
__global__ void k_count(const int* __restrict__ lid, int n, int* __restrict__ cnt) {
    __shared__ int h4[4];
    int i = blockIdx.x * blockDim.x + threadIdx.x;
    if (threadIdx.x < 4) h4[threadIdx.x] = 0;
    __syncthreads();
    if (i < n) atomicAdd(&h4[lid[i] & 3], 1);
    __syncthreads();
    if (threadIdx.x < 4) atomicAdd(&cnt[threadIdx.x], h4[threadIdx.x]);
}

__global__ void k_offsets(const int* __restrict__ cnt, int* __restrict__ cursor) {
    if (threadIdx.x == 0 && blockIdx.x == 0) {
        int off = 0;
        for (int k = 0; k < 4; k++) {
            cursor[k] = off;
            off = (off + cnt[k] + 63) & ~63;
        }
    }
}

__global__ void k_scatter(const int* __restrict__ lid, int n, int* __restrict__ cursor, int* __restrict__ perm) {
    int i = blockIdx.x * blockDim.x + threadIdx.x;
    if (i >= n) return;
    int lane = threadIdx.x & 63;
    int c = lid[i] & 3;
    unsigned long long m0 = __ballot(c == 0), m1 = __ballot(c == 1);
    unsigned long long m2 = __ballot(c == 2), m3 = __ballot(c == 3);
    unsigned long long mc = (c == 0) ? m0 : (c == 1) ? m1 : (c == 2) ? m2 : m3;
    int rank = __popcll(mc & ((1ull << lane) - 1ull));
    int cntl = (lane == 0) ? __popcll(m0) : (lane == 1) ? __popcll(m1) : (lane == 2) ? __popcll(m2) : __popcll(m3);
    int basev = 0;
    if (lane < 4) basev = atomicAdd(&cursor[lane], cntl);
    int base = __shfl(basev, c, 64);
    perm[base + rank] = i;
}

// ---------------- pack embedding table to bf16: T[l][g] = (bf16(e.x), bf16(e.y)) ----------------
__global__ __launch_bounds__(256) void k_packtab(const float* __restrict__ emb, uint32_t* __restrict__ T) {
    const int i = blockIdx.x * 256 + threadIdx.x;
    float2 e = ((const float2*)emb)[i];
    T[i] = f2bf(e.x) | (f2bf(e.y) << 16);
}

// ---------------- weight prep: transpose + bf16 ----------------
// blocks 0..191: Wres [c][ib][k][n] fp32 -> Wrt [c][ib][n][k] bf16 (64x64 tiles)
// blocks 192..195: W0 [c][32][256] fp32 -> W0t [c][256][32] bf16
__global__ __launch_bounds__(256) void k_prep(const float* __restrict__ Wres, const float* __restrict__ W0,
                                              uint16_t* __restrict__ Wrt, uint16_t* __restrict__ W0t) {
    __shared__ float sm[64 * 65 > 32 * 257 ? 64 * 65 : 32 * 257];
    const int t = threadIdx.x;
    const int bid = blockIdx.x;
    if (bid < 192) {
        const int c = bid / 48, rem = bid % 48, ib = rem / 16, tile = rem % 16;
        const int n0 = (tile / 4) * 64, k0 = (tile % 4) * 64;
        const float* src = Wres + (size_t)(c * 3 + ib) * 65536;
        for (int i = 0; i < 16; i++) {
            int idx = t + 256 * i, r = idx >> 6, cc = idx & 63;
            sm[r * 65 + cc] = src[(size_t)(k0 + r) * 256 + n0 + cc];
        }
        __syncthreads();
        uint16_t* dst = Wrt + (size_t)(c * 3 + ib) * 65536;
        for (int i = 0; i < 16; i++) {
            int idx = t + 256 * i, rn = idx >> 6, ck = idx & 63;
            dst[(size_t)(n0 + rn) * 256 + k0 + ck] = (uint16_t)f2bf(sm[ck * 65 + rn]);
        }
    } else {
        const int c = bid - 192;
        for (int i = 0; i < 32; i++) {
            int idx = t + 256 * i, k = idx >> 8, n = idx & 255;
            sm[k * 257 + n] = W0[(size_t)c * 8192 + idx];
        }
        __syncthreads();
        for (int i = 0; i < 32; i++) {
            int idx = t + 256 * i, n = idx >> 5, k = idx & 31;
            W0t[(size_t)c * 8192 + idx] = (uint16_t)f2bf(sm[k * 257 + n]);
        }
    }
}

// ---------------- encode kernel: one level per block, level -> XCD pinned ----------------
// Dim0 prime = 1, so the dim0 vertex pair is {h, h^mask} with mask = bl0^(bl0+1).
// mask<=3 (75% of points): both entries in one 16B quad -> single dwordx4.
// mask in {7,15} (19%): second quad is in the SAME 64B line -> 2 reqs, 1 line fill.
// Only ~6% of points touch 2 lines per pair. Avg ~40 reqs / ~35 lines per point-level.
// NOTE: launch_bounds must stay (256,4): (256,8) caps VGPRs at 64 -> the compiler
// spilled to scratch (R6: WRITE_SIZE 33MB->5.6GB, 3x regression).
__global__ __launch_bounds__(256, 4) void k_encode(
    const float* __restrict__ x, const uint32_t* __restrict__ T,
    uint32_t* __restrict__ encP, int B)
{
    __shared__ float xs[256 * 6];
    const int t = threadIdx.x;
    const int NC8 = (B >> 8) << 3;
    const int pass = (blockIdx.x >= NC8) ? 1 : 0;
    const int rem  = blockIdx.x - pass * NC8;
    const int l    = (rem & 7) + (pass << 3);
    const int chunk = rem >> 3;
    const int pbase = chunk << 8;

    for (int idx = t; idx < 256 * 6; idx += 256) {
        float v = x[(size_t)pbase * 6 + idx];
        xs[idx] = fminf(fmaxf(v, 0.f), 1.f);
    }
    __syncthreads();

    const float res  = RESF[l];
    const float grid = GRIDF[l];
    float wv[6]; uint32_t ua[6], ub[6];
    #pragma unroll
    for (int d = 0; d < 6; d++) {
        float xv  = xs[t * 6 + d];
        float blf = floorf(xv * res);
        float w   = (xv - blf * grid) / (grid + 1e-6f);
        wv[d] = fminf(fmaxf(w, 0.f), 1.f);
        uint32_t uu = (uint32_t)(int)blf * PRS[d];
        ua[d] = uu; ub[d] = uu + PRS[d];
    }
    // v = (i<<4)|(j<<2)|k. Hash: dims (0,1)<-i, (2,3)<-j, (4,5)<-k (MSB-first).
    // Weights LSB-first: hash-dim0<->wv[5], dim1<->wv[4], dim2<->wv[3], dim3<->wv[2],
    // dim4<->wv[1], dim5<->wv[0] — faithful to the reference's bit-order mismatch.
    uint32_t HJ[4], HK[4]; float WJ[4], WK[4];
    #pragma unroll
    for (int q = 0; q < 4; q++) {
        const int b1 = (q >> 1) & 1, bb = q & 1;
        HJ[q] = (b1 ? ub[2] : ua[2]) ^ (bb ? ub[3] : ua[3]);
        HK[q] = (b1 ? ub[4] : ua[4]) ^ (bb ? ub[5] : ua[5]);
        WJ[q] = (bb ? wv[2] : 1.f - wv[2]) * (b1 ? wv[3] : 1.f - wv[3]);
        WK[q] = (bb ? wv[0] : 1.f - wv[0]) * (b1 ? wv[1] : 1.f - wv[1]);
    }
    const uint32_t D1[2] = {ua[1], ub[1]};
    const float   WD1[2] = {1.f - wv[4], wv[4]};
    const float w5a = 1.f - wv[5], w5b = wv[5];   // dim0 beta weights
    const uint32_t bl0  = ua[0];                  // prime = 1
    const uint32_t mask = bl0 ^ (bl0 + 1u);       // XOR delta of the dim0 vertex pair
    const bool narrow = (mask <= 3u);             // both vertices within one 16B quad
    const uint4* __restrict__ Tl4 = reinterpret_cast<const uint4*>(T + (size_t)l * HTABLE);

    float f0 = 0.f, f1 = 0.f;
    #pragma unroll
    for (int j1 = 0; j1 < 2; j1++) {
        #pragma unroll
        for (int j = 0; j < 4; j++) {
            const uint32_t Sj = D1[j1] ^ HJ[j];
            const float   wj = WD1[j1] * WJ[j];
            #pragma unroll
            for (int k = 0; k < 4; k++) {
                const uint32_t h  = (bl0 ^ Sj ^ HK[k]) & TMASK;
                const uint32_t h2 = h ^ mask;      // mask < 2^10, stays in-table
                const float wS = wj * WK[k];
                const uint4 La = Tl4[h >> 2];
                const uint32_t pa = sel4(La, h & 3u);            // E[bl0^S]
                uint32_t pb = sel4(La, h2 & 3u);                 // valid when narrow
                if (!narrow) {                                   // exec-masked wide path
                    const uint4 Lb = Tl4[h2 >> 2];
                    pb = sel4(Lb, h2 & 3u);
                }
                const float e0x = __uint_as_float(pa << 16),  e0y = __uint_as_float(pa & 0xFFFF0000u);
                const float e1x = __uint_as_float(pb << 16),  e1y = __uint_as_float(pb & 0xFFFF0000u);
                f0 = fmaf(wS, fmaf(w5a, e0x, w5b * e1x), f0);
                f1 = fmaf(wS, fmaf(w5a, e0y, w5b * e1y), f1);
            }
        }
    }
    encP[(size_t)l * B + pbase + t] = f2bf(f0) | (f2bf(f1) << 16);
}

// ---------------- MFMA MLP ----------------
// Per block: 64 class-uniform points. GEMMs computed as D[n=neuron][m=point] = W^T . H
// so C/D regs (4 consecutive neurons) are k-contiguous for the next layer's B operand.
// Wave wv owns neurons [wv*64, wv*64+64); fp32 residual carry lives in h_reg.
__global__ __launch_bounds__(256, 2) void k_mlp2(
    const int* __restrict__ lid, const uint32_t* __restrict__ encP,
    const uint16_t* __restrict__ W0t, const float* __restrict__ b0,
    const uint16_t* __restrict__ Wrt, const float* __restrict__ bres,
    const float* __restrict__ scales, const float* __restrict__ Wout, const float* __restrict__ bout,
    const int* __restrict__ perm, float* __restrict__ out, int B)
{
    __shared__ uint16_t hB[64 * KSTR];     // 33792 B  H as [point][k] bf16
    __shared__ uint16_t encB[64 * KE];     //  5120 B  enc as [point][k32] bf16
    __shared__ float    bs[256];           //  per-layer bias / Wout stage
    __shared__ float    outP[256];
    __shared__ int      permL[TILE];

    const int t  = threadIdx.x;
    const int lane = t & 63;
    const int wv = t >> 6;          // wave id: neuron slice
    const int mi = lane & 15;       // point within 16-col
    const int q  = lane >> 4;       // quad

    if (t < TILE) permL[t] = perm[(size_t)blockIdx.x * TILE + t];
    __syncthreads();
    const int g0 = permL[0];
    if (g0 < 0) return;
    const int c = lid[g0] & 3;

    // stage enc [point][k=2l..2l+1] and b0
    bs[t] = b0[c * 256 + t];
    for (int idx = t; idx < 16 * 64; idx += 256) {
        const int l = idx >> 6, pp = idx & 63;
        const int gi = permL[pp];
        ((uint32_t*)encB)[pp * (KE / 2) + l] = (gi >= 0) ? encP[(size_t)l * B + gi] : 0u;
    }
    __syncthreads();

    floatx4 acc[4][4];
    floatx4 h_reg[4][4];

    // ---- layer 0: D = W0^T(256x32) . enc(32x64)
    {
        #pragma unroll
        for (int mt = 0; mt < 4; mt++)
            #pragma unroll
            for (int nt = 0; nt < 4; nt++) acc[mt][nt] = (floatx4){0.f, 0.f, 0.f, 0.f};
        const short8* Wp = (const short8*)(W0t + (size_t)c * 8192);
        short8 A[4], Bf[4];
        #pragma unroll
        for (int mt = 0; mt < 4; mt++) A[mt] = Wp[(wv * 64 + mt * 16 + mi) * 4 + q];
        #pragma unroll
        for (int nt = 0; nt < 4; nt++) Bf[nt] = *(const short8*)&encB[(nt * 16 + mi) * KE + q * 8];
        #pragma unroll
        for (int mt = 0; mt < 4; mt++)
            #pragma unroll
            for (int nt = 0; nt < 4; nt++)
                acc[mt][nt] = __builtin_amdgcn_mfma_f32_16x16x32_bf16(A[mt], Bf[nt], acc[mt][nt], 0, 0, 0);
        // h = relu(u + b0); write bf16 to hB
        #pragma unroll
        for (int mt = 0; mt < 4; mt++) {
            const int nb = wv * 64 + mt * 16 + q * 4;
            #pragma unroll
            for (int nt = 0; nt < 4; nt++) {
                floatx4 u = acc[mt][nt], h;
                h[0] = relu_(u[0] + bs[nb + 0]); h[1] = relu_(u[1] + bs[nb + 1]);
                h[2] = relu_(u[2] + bs[nb + 2]); h[3] = relu_(u[3] + bs[nb + 3]);
                h_reg[mt][nt] = h;
                uint2 pk; pk.x = f2bf(h[0]) | (f2bf(h[1]) << 16); pk.y = f2bf(h[2]) | (f2bf(h[3]) << 16);
                *(uint2*)&hB[(nt * 16 + mi) * KSTR + nb] = pk;
            }
        }
    }
    __syncthreads();

    // ---- 3 scaled residual blocks
    #pragma unroll 1
    for (int ib = 0; ib < 3; ib++) {
        bs[t] = bres[(size_t)((c * 3 + ib) << 8) + t];   // read after the post-MFMA barrier
        const float s = scales[c * 3 + ib];
        #pragma unroll
        for (int mt = 0; mt < 4; mt++)
            #pragma unroll
            for (int nt = 0; nt < 4; nt++) acc[mt][nt] = (floatx4){0.f, 0.f, 0.f, 0.f};

        const short8* Wp = (const short8*)(Wrt + (size_t)(c * 3 + ib) * 65536);
        short8 Acur[4], Anext[4], Bf[4];
        #pragma unroll
        for (int mt = 0; mt < 4; mt++) Acur[mt] = Wp[(wv * 64 + mt * 16 + mi) * 32 + q];
        #pragma unroll 1
        for (int ks = 0; ks < 8; ks++) {
            #pragma unroll
            for (int nt = 0; nt < 4; nt++)
                Bf[nt] = *(const short8*)&hB[(nt * 16 + mi) * KSTR + ks * 32 + q * 8];
            if (ks < 7) {
                #pragma unroll
                for (int mt = 0; mt < 4; mt++)
                    Anext[mt] = Wp[(wv * 64 + mt * 16 + mi) * 32 + (ks + 1) * 4 + q];
            }
            #pragma unroll
            for (int mt = 0; mt < 4; mt++)
                #pragma unroll
                for (int nt = 0; nt < 4; nt++)
                    acc[mt][nt] = __builtin_amdgcn_mfma_f32_16x16x32_bf16(Acur[mt], Bf[nt], acc[mt][nt], 0, 0, 0);
            #pragma unroll
            for (int mt = 0; mt < 4; mt++) Acur[mt] = Anext[mt];
        }
        __syncthreads();   // hB reads done; bs staged
        #pragma unroll
        for (int mt = 0; mt < 4; mt++) {
            const int nb = wv * 64 + mt * 16 + q * 4;
            #pragma unroll
            for (int nt = 0; nt < 4; nt++) {
                floatx4 u = acc[mt][nt];
                floatx4 h = h_reg[mt][nt];
                h[0] = fmaf(s, relu_(u[0] + bs[nb + 0]), h[0]);
                h[1] = fmaf(s, relu_(u[1] + bs[nb + 1]), h[1]);
                h[2] = fmaf(s, relu_(u[2] + bs[nb + 2]), h[2]);
                h[3] = fmaf(s, relu_(u[3] + bs[nb + 3]), h[3]);
                h_reg[mt][nt] = h;
                if (ib < 2) {
                    uint2 pk; pk.x = f2bf(h[0]) | (f2bf(h[1]) << 16); pk.y = f2bf(h[2]) | (f2bf(h[3]) << 16);
                    *(uint2*)&hB[(nt * 16 + mi) * KSTR + nb] = pk;
                }
            }
        }
        if (ib < 2) __syncthreads();
    }

    // ---- output layer: out[p] = sum_n h[n][p] * Wout[n] + bout
    __syncthreads();
    bs[t] = Wout[c * 256 + t];
    __syncthreads();
    float po[4] = {0.f, 0.f, 0.f, 0.f};
    #pragma unroll
    for (int mt = 0; mt < 4; mt++) {
        const int nb = wv * 64 + mt * 16 + q * 4;
        const float w0v = bs[nb + 0], w1v = bs[nb + 1], w2v = bs[nb + 2], w3v = bs[nb + 3];
        #pragma unroll
        for (int nt = 0; nt < 4; nt++) {
            const floatx4 h = h_reg[mt][nt];
            po[nt] += h[0] * w0v + h[1] * w1v + h[2] * w2v + h[3] * w3v;
        }
    }
    #pragma unroll
    for (int nt = 0; nt < 4; nt++) {
        float v = po[nt];
        v += __shfl_xor(v, 16, 64);
        v += __shfl_xor(v, 32, 64);
        if (q == 0) outP[wv * 64 + nt * 16 + mi] = v;
    }
    __syncthreads();
    if (t < TILE) {
        float r = outP[t] + outP[64 + t] + outP[128 + t] + outP[192 + t] + bout[c];
        const int gi = permL[t];
        if (gi >= 0) out[gi] = r;
    }
}

extern "C" void kernel_launch(void* const* d_in, const int* in_sizes, int n_in,
                              void* d_out, int out_size, void* d_ws, size_t ws_size,
                              hipStream_t stream) {
    const float* x      = (const float*)d_in[0];
    const int*   lid    = (const int*)  d_in[1];
    const float* emb    = (const float*)d_in[2];
    const float* W0     = (const float*)d_in[3];
    const float* b0     = (const float*)d_in[4];
    const float* Wres   = (const float*)d_in[5];
    const float* bres   = (const float*)d_in[6];
    const float* scales = (const float*)d_in[7];
    const float* Wout   = (const float*)d_in[8];
    const float* bout   = (const float*)d_in[9];
    float* out = (float*)d_out;

    const int B = in_sizes[1];                          // 524288 points
    int* cnt    = (int*)d_ws;                           // [0..3]
    int* cursor = cnt + 4;                              // [4..7]
    int* perm   = cnt + 64;                             // +256 B, padded permutation (~2.1 MB)
    uint16_t* W0t = (uint16_t*)((char*)d_ws + 2228224); // +2.125 MB: [4][256][32] bf16 (64 KB)
    uint16_t* Wrt = (uint16_t*)((char*)d_ws + 2359296); // +2.25 MB: [4][3][256][256] bf16 (1.5 MB)
    uint32_t* encP = (uint32_t*)((char*)d_ws + (4u << 20));   // +4 MB: [16][B] packed bf16 pairs (32 MB)
    uint32_t* T    = (uint32_t*)((char*)d_ws + (36u << 20));  // +36 MB: bf16 pair table [16][2^19] (32 MB)
    const int nblk = B / TILE + 4;                      // 8196

    (void)hipMemsetAsync(d_ws, 0, 32, stream);
    (void)hipMemsetAsync(perm, 0xFF, (size_t)nblk * TILE * sizeof(int), stream);
    k_packtab<<<(16 * (int)HTABLE) / 256, 256, 0, stream>>>(emb, T);
    k_prep   <<<196, 256, 0, stream>>>(Wres, W0, Wrt, W0t);
    k_count  <<<B / 256, 256, 0, stream>>>(lid, B, cnt);
    k_offsets<<<1, 64, 0, stream>>>(cnt, cursor);
    k_scatter<<<B / 256, 256, 0, stream>>>(lid, B, cursor, perm);
    k_encode <<<(B / 256) * 16, 256, 0, stream>>>(x, T, encP, B);
    k_mlp2   <<<nblk, 256, 0, stream>>>(lid, encP, W0t, b0, Wrt, bres, scales, Wout, bout, perm, out, B);
}

// Round 8
// 1985.696 us; speedup vs baseline: 2.3140x; 1.3110x over previous
//
#include <hip/hip_runtime.h>
#include <stdint.h>

#define HTABLE (1u << 19)
#define TMASK  (HTABLE - 1u)
#define TILE   64
#define KSTR   264   // hB row stride in bf16 elems (528 B: 16B-aligned, 2-way-free banks)
#define KE     40    // encB row stride in bf16 elems

typedef __attribute__((ext_vector_type(8))) short short8;
typedef __attribute__((ext_vector_type(4))) float floatx4;

__device__ __forceinline__ float relu_(float v) { return fmaxf(v, 0.f); }

__device__ __forceinline__ uint32_t f2bf(float f) {
    uint32_t u = __float_as_uint(f);
    return (u + 0x7FFFu + ((u >> 16) & 1u)) >> 16;
}
__device__ __forceinline__ float bf2f(uint32_t h) { return __uint_as_float(h << 16); }

// variable-index extract from a 16B quad: 3 cndmasks, no scratch
__device__ __forceinline__ uint32_t sel4(const uint4& v, uint32_t i) {
    uint32_t lo = (i & 1u) ? v.y : v.x;
    uint32_t hi = (i & 1u) ? v.w : v.z;
    return (i & 2u) ? hi : lo;
}

__device__ __constant__ uint32_t PRS[6] = {1u, 2654435761u, 805459861u, 3674653429u, 2097192037u, 1434869437u};
__device__ __constant__ float RESF[16]  = {16.f,20.f,25.f,32.f,40.f,50.f,64.f,80.f,101.f,128.f,161.f,203.f,256.f,322.f,406.f,512.f};
__device__ __constant__ float GRIDF[16] = {1.f/16.f,1.f/20.f,1.f/25.f,1.f/32.f,1.f/40.f,1.f/50.f,1.f/64.f,1.f/80.f,
                                           1.f/101.f,1.f/128.f,1.f/161.f,1.f/203.f,1.f/256.f,1.f/322.f,1.f/406.f,1.f/512.f};

// ---------------- binning kernels ----------------
__global__ void k_count(const int* __restrict__ lid, int n, int* __restrict__ cnt) {
    __shared__ int h4[4];
    int i = blockIdx.x * blockDim.x + threadIdx.x;
    if (threadIdx.x < 4) h4[threadIdx.x] = 0;
    __syncthreads();
    if (i < n) atomicAdd(&h4[lid[i] & 3], 1);
    __syncthreads();
    if (threadIdx.x < 4) atomicAdd(&cnt[threadIdx.x], h4[threadIdx.x]);
}

__global__ void k_offsets(const int* __restrict__ cnt, int* __restrict__ cursor) {
    if (threadIdx.x == 0 && blockIdx.x == 0) {
        int off = 0;
        for (int k = 0; k < 4; k++) {
            cursor[k] = off;
            off = (off + cnt[k] + 63) & ~63;
        }
    }
}

__global__ void k_scatter(const int* __restrict__ lid, int n, int* __restrict__ cursor, int* __restrict__ perm) {
    int i = blockIdx.x * blockDim.x + threadIdx.x;
    if (i >= n) return;
    int lane = threadIdx.x & 63;
    int c = lid[i] & 3;
    unsigned long long m0 = __ballot(c == 0), m1 = __ballot(c == 1);
    unsigned long long m2 = __ballot(c == 2), m3 = __ballot(c == 3);
    unsigned long long mc = (c == 0) ? m0 : (c == 1) ? m1 : (c == 2) ? m2 : m3;
    int rank = __popcll(mc & ((1ull << lane) - 1ull));
    int cntl = (lane == 0) ? __popcll(m0) : (lane == 1) ? __popcll(m1) : (lane == 2) ? __popcll(m2) : __popcll(m3);
    int basev = 0;
    if (lane < 4) basev = atomicAdd(&cursor[lane], cntl);
    int base = __shfl(basev, c, 64);
    perm[base + rank] = i;
}

// ---------------- pack embedding table to bf16: T[l][g] = (bf16(e.x), bf16(e.y)) ----------------
__global__ __launch_bounds__(256) void k_packtab(const float* __restrict__ emb, uint32_t* __restrict__ T) {
    const int i = blockIdx.x * 256 + threadIdx.x;
    float2 e = ((const float2*)emb)[i];
    T[i] = f2bf(e.x) | (f2bf(e.y) << 16);
}

// ---------------- weight prep: transpose + bf16 ----------------
// blocks 0..191: Wres [c][ib][k][n] fp32 -> Wrt [c][ib][n][k] bf16 (64x64 tiles)
// blocks 192..195: W0 [c][32][256] fp32 -> W0t [c][256][32] bf16
__global__ __launch_bounds__(256) void k_prep(const float* __restrict__ Wres, const float* __restrict__ W0,
                                              uint16_t* __restrict__ Wrt, uint16_t* __restrict__ W0t) {
    __shared__ float sm[64 * 65 > 32 * 257 ? 64 * 65 : 32 * 257];
    const int t = threadIdx.x;
    const int bid = blockIdx.x;
    if (bid < 192) {
        const int c = bid / 48, rem = bid % 48, ib = rem / 16, tile = rem % 16;
        const int n0 = (tile / 4) * 64, k0 = (tile % 4) * 64;
        const float* src = Wres + (size_t)(c * 3 + ib) * 65536;
        for (int i = 0; i < 16; i++) {
            int idx = t + 256 * i, r = idx >> 6, cc = idx & 63;
            sm[r * 65 + cc] = src[(size_t)(k0 + r) * 256 + n0 + cc];
        }
        __syncthreads();
        uint16_t* dst = Wrt + (size_t)(c * 3 + ib) * 65536;
        for (int i = 0; i < 16; i++) {
            int idx = t + 256 * i, rn = idx >> 6, ck = idx & 63;
            dst[(size_t)(n0 + rn) * 256 + k0 + ck] = (uint16_t)f2bf(sm[ck * 65 + rn]);
        }
    } else {
        const int c = bid - 192;
        for (int i = 0; i < 32; i++) {
            int idx = t + 256 * i, k = idx >> 8, n = idx & 255;
            sm[k * 257 + n] = W0[(size_t)c * 8192 + idx];
        }
        __syncthreads();
        for (int i = 0; i < 32; i++) {
            int idx = t + 256 * i, n = idx >> 5, k = idx & 31;
            W0t[(size_t)c * 8192 + idx] = (uint16_t)f2bf(sm[k * 257 + n]);
        }
    }
}

// ---------------- encode kernel: one level per block, level -> XCD pinned ----------------
// Dim0 prime = 1, so the dim0 vertex pair is {h, h^mask} with mask = bl0^(bl0+1).
// mask<=3 (75% of points): both entries in one 16B quad -> single dwordx4.
// mask in {7,15} (19%): second quad is in the SAME 64B line -> 2 reqs, 1 line fill.
// REGISTER-PRESSURE NOTE (R6/R7 lesson): uint4 quad loads are 4 VGPRs each; a fully
// unrolled 32-load gather keeps ~128+ result VGPRs live -> compiler spills to scratch
// (R7: 5.3 GB HBM scratch traffic, 2x regression vs R5). The jj-loop below is
// #pragma unroll 2 so at most ~2x6 quads are in flight (~90 VGPR total, no spill).
__global__ __launch_bounds__(256, 4) void k_encode(
    const float* __restrict__ x, const uint32_t* __restrict__ T,
    uint32_t* __restrict__ encP, int B)
{
    __shared__ float xs[256 * 6];
    const int t = threadIdx.x;
    const int NC8 = (B >> 8) << 3;
    const int pass = (blockIdx.x >= NC8) ? 1 : 0;
    const int rem  = blockIdx.x - pass * NC8;
    const int l    = (rem & 7) + (pass << 3);
    const int chunk = rem >> 3;
    const int pbase = chunk << 8;

    for (int idx = t; idx < 256 * 6; idx += 256) {
        float v = x[(size_t)pbase * 6 + idx];
        xs[idx] = fminf(fmaxf(v, 0.f), 1.f);
    }
    __syncthreads();

    const float res  = RESF[l];
    const float grid = GRIDF[l];
    float wv[6]; uint32_t ua[6], ub[6];
    #pragma unroll
    for (int d = 0; d < 6; d++) {
        float xv  = xs[t * 6 + d];
        float blf = floorf(xv * res);
        float w   = (xv - blf * grid) / (grid + 1e-6f);
        wv[d] = fminf(fmaxf(w, 0.f), 1.f);
        uint32_t uu = (uint32_t)(int)blf * PRS[d];
        ua[d] = uu; ub[d] = uu + PRS[d];
    }
    // v = (i<<4)|(j<<2)|k. Hash: dims (0,1)<-i, (2,3)<-j, (4,5)<-k (MSB-first).
    // Weights LSB-first: hash-dim0<->wv[5], dim1<->wv[4], dim2<->wv[3], dim3<->wv[2],
    // dim4<->wv[1], dim5<->wv[0] — faithful to the reference's bit-order mismatch.
    uint32_t HK[4]; float WK[4];
    #pragma unroll
    for (int q = 0; q < 4; q++) {
        const int b1 = (q >> 1) & 1, bb = q & 1;
        HK[q] = (b1 ? ub[4] : ua[4]) ^ (bb ? ub[5] : ua[5]);
        WK[q] = (bb ? wv[0] : 1.f - wv[0]) * (b1 ? wv[1] : 1.f - wv[1]);
    }
    // 8 combos of dim1 x (dims 2,3)
    uint32_t S8[8]; float W8[8];
    #pragma unroll
    for (int jj = 0; jj < 8; jj++) {
        const int j1 = jj >> 2, j = jj & 3;
        const int b1 = (j >> 1) & 1, bb = j & 1;
        const uint32_t hj = (b1 ? ub[2] : ua[2]) ^ (bb ? ub[3] : ua[3]);
        const float  wj = ((bb ? wv[2] : 1.f - wv[2]) * (b1 ? wv[3] : 1.f - wv[3]));
        S8[jj] = (j1 ? ub[1] : ua[1]) ^ hj;
        W8[jj] = (j1 ? wv[4] : 1.f - wv[4]) * wj;
    }
    const float w5a = 1.f - wv[5], w5b = wv[5];   // dim0 beta weights
    const uint32_t bl0  = ua[0];                  // prime = 1
    const uint32_t mask = bl0 ^ (bl0 + 1u);       // XOR delta of the dim0 vertex pair
    const bool narrow = (mask <= 3u);             // both vertices within one 16B quad
    const uint4* __restrict__ Tl4 = reinterpret_cast<const uint4*>(T + (size_t)l * HTABLE);

    float f0 = 0.f, f1 = 0.f;
    #pragma unroll 2
    for (int jj = 0; jj < 8; jj++) {
        const uint32_t Sj = S8[jj];
        const float   wj = W8[jj];
        #pragma unroll
        for (int k = 0; k < 4; k++) {
            const uint32_t h  = (bl0 ^ Sj ^ HK[k]) & TMASK;
            const uint32_t h2 = h ^ mask;      // mask < 2^10, stays in-table
            const float wS = wj * WK[k];
            const uint4 La = Tl4[h >> 2];
            const uint32_t pa = sel4(La, h & 3u);            // E[bl0^S]
            uint32_t pb = sel4(La, h2 & 3u);                 // valid when narrow
            if (!narrow) {                                   // exec-masked wide path
                const uint4 Lb = Tl4[h2 >> 2];
                pb = sel4(Lb, h2 & 3u);
            }
            const float e0x = __uint_as_float(pa << 16),  e0y = __uint_as_float(pa & 0xFFFF0000u);
            const float e1x = __uint_as_float(pb << 16),  e1y = __uint_as_float(pb & 0xFFFF0000u);
            f0 = fmaf(wS, fmaf(w5a, e0x, w5b * e1x), f0);
            f1 = fmaf(wS, fmaf(w5a, e0y, w5b * e1y), f1);
        }
    }
    encP[(size_t)l * B + pbase + t] = f2bf(f0) | (f2bf(f1) << 16);
}

// ---------------- MFMA MLP ----------------
// Per block: 64 class-uniform points. GEMMs computed as D[n=neuron][m=point] = W^T . H
// so C/D regs (4 consecutive neurons) are k-contiguous for the next layer's B operand.
// Wave wv owns neurons [wv*64, wv*64+64); fp32 residual carry lives in h_reg.
__global__ __launch_bounds__(256, 2) void k_mlp2(
    const int* __restrict__ lid, const uint32_t* __restrict__ encP,
    const uint16_t* __restrict__ W0t, const float* __restrict__ b0,
    const uint16_t* __restrict__ Wrt, const float* __restrict__ bres,
    const float* __restrict__ scales, const float* __restrict__ Wout, const float* __restrict__ bout,
    const int* __restrict__ perm, float* __restrict__ out, int B)
{
    __shared__ uint16_t hB[64 * KSTR];     // 33792 B  H as [point][k] bf16
    __shared__ uint16_t encB[64 * KE];     //  5120 B  enc as [point][k32] bf16
    __shared__ float    bs[256];           //  per-layer bias / Wout stage
    __shared__ float    outP[256];
    __shared__ int      permL[TILE];

    const int t  = threadIdx.x;
    const int lane = t & 63;
    const int wv = t >> 6;          // wave id: neuron slice
    const int mi = lane & 15;       // point within 16-col
    const int q  = lane >> 4;       // quad

    if (t < TILE) permL[t] = perm[(size_t)blockIdx.x * TILE + t];
    __syncthreads();
    const int g0 = permL[0];
    if (g0 < 0) return;
    const int c = lid[g0] & 3;

    // stage enc [point][k=2l..2l+1] and b0
    bs[t] = b0[c * 256 + t];
    for (int idx = t; idx < 16 * 64; idx += 256) {
        const int l = idx >> 6, pp = idx & 63;
        const int gi = permL[pp];
        ((uint32_t*)encB)[pp * (KE / 2) + l] = (gi >= 0) ? encP[(size_t)l * B + gi] : 0u;
    }
    __syncthreads();

    floatx4 acc[4][4];
    floatx4 h_reg[4][4];

    // ---- layer 0: D = W0^T(256x32) . enc(32x64)
    {
        #pragma unroll
        for (int mt = 0; mt < 4; mt++)
            #pragma unroll
            for (int nt = 0; nt < 4; nt++) acc[mt][nt] = (floatx4){0.f, 0.f, 0.f, 0.f};
        const short8* Wp = (const short8*)(W0t + (size_t)c * 8192);
        short8 A[4], Bf[4];
        #pragma unroll
        for (int mt = 0; mt < 4; mt++) A[mt] = Wp[(wv * 64 + mt * 16 + mi) * 4 + q];
        #pragma unroll
        for (int nt = 0; nt < 4; nt++) Bf[nt] = *(const short8*)&encB[(nt * 16 + mi) * KE + q * 8];
        #pragma unroll
        for (int mt = 0; mt < 4; mt++)
            #pragma unroll
            for (int nt = 0; nt < 4; nt++)
                acc[mt][nt] = __builtin_amdgcn_mfma_f32_16x16x32_bf16(A[mt], Bf[nt], acc[mt][nt], 0, 0, 0);
        // h = relu(u + b0); write bf16 to hB
        #pragma unroll
        for (int mt = 0; mt < 4; mt++) {
            const int nb = wv * 64 + mt * 16 + q * 4;
            #pragma unroll
            for (int nt = 0; nt < 4; nt++) {
                floatx4 u = acc[mt][nt], h;
                h[0] = relu_(u[0] + bs[nb + 0]); h[1] = relu_(u[1] + bs[nb + 1]);
                h[2] = relu_(u[2] + bs[nb + 2]); h[3] = relu_(u[3] + bs[nb + 3]);
                h_reg[mt][nt] = h;
                uint2 pk; pk.x = f2bf(h[0]) | (f2bf(h[1]) << 16); pk.y = f2bf(h[2]) | (f2bf(h[3]) << 16);
                *(uint2*)&hB[(nt * 16 + mi) * KSTR + nb] = pk;
            }
        }
    }
    __syncthreads();

    // ---- 3 scaled residual blocks
    #pragma unroll 1
    for (int ib = 0; ib < 3; ib++) {
        bs[t] = bres[(size_t)((c * 3 + ib) << 8) + t];   // read after the post-MFMA barrier
        const float s = scales[c * 3 + ib];
        #pragma unroll
        for (int mt = 0; mt < 4; mt++)
            #pragma unroll
            for (int nt = 0; nt < 4; nt++) acc[mt][nt] = (floatx4){0.f, 0.f, 0.f, 0.f};

        const short8* Wp = (const short8*)(Wrt + (size_t)(c * 3 + ib) * 65536);
        short8 Acur[4], Anext[4], Bf[4];
        #pragma unroll
        for (int mt = 0; mt < 4; mt++) Acur[mt] = Wp[(wv * 64 + mt * 16 + mi) * 32 + q];
        #pragma unroll 1
        for (int ks = 0; ks < 8; ks++) {
            #pragma unroll
            for (int nt = 0; nt < 4; nt++)
                Bf[nt] = *(const short8*)&hB[(nt * 16 + mi) * KSTR + ks * 32 + q * 8];
            if (ks < 7) {
                #pragma unroll
                for (int mt = 0; mt < 4; mt++)
                    Anext[mt] = Wp[(wv * 64 + mt * 16 + mi) * 32 + (ks + 1) * 4 + q];
            }
            #pragma unroll
            for (int mt = 0; mt < 4; mt++)
                #pragma unroll
                for (int nt = 0; nt < 4; nt++)
                    acc[mt][nt] = __builtin_amdgcn_mfma_f32_16x16x32_bf16(Acur[mt], Bf[nt], acc[mt][nt], 0, 0, 0);
            #pragma unroll
            for (int mt = 0; mt < 4; mt++) Acur[mt] = Anext[mt];
        }
        __syncthreads();   // hB reads done; bs staged
        #pragma unroll
        for (int mt = 0; mt < 4; mt++) {
            const int nb = wv * 64 + mt * 16 + q * 4;
            #pragma unroll
            for (int nt = 0; nt < 4; nt++) {
                floatx4 u = acc[mt][nt];
                floatx4 h = h_reg[mt][nt];
                h[0] = fmaf(s, relu_(u[0] + bs[nb + 0]), h[0]);
                h[1] = fmaf(s, relu_(u[1] + bs[nb + 1]), h[1]);
                h[2] = fmaf(s, relu_(u[2] + bs[nb + 2]), h[2]);
                h[3] = fmaf(s, relu_(u[3] + bs[nb + 3]), h[3]);
                h_reg[mt][nt] = h;
                if (ib < 2) {
                    uint2 pk; pk.x = f2bf(h[0]) | (f2bf(h[1]) << 16); pk.y = f2bf(h[2]) | (f2bf(h[3]) << 16);
                    *(uint2*)&hB[(nt * 16 + mi) * KSTR + nb] = pk;
                }
            }
        }
        if (ib < 2) __syncthreads();
    }

    // ---- output layer: out[p] = sum_n h[n][p] * Wout[n] + bout
    __syncthreads();
    bs[t] = Wout[c * 256 + t];
    __syncthreads();
    float po[4] = {0.f, 0.f, 0.f, 0.f};
    #pragma unroll
    for (int mt = 0; mt < 4; mt++) {
        const int nb = wv * 64 + mt * 16 + q * 4;
        const float w0v = bs[nb + 0], w1v = bs[nb + 1], w2v = bs[nb + 2], w3v = bs[nb + 3];
        #pragma unroll
        for (int nt = 0; nt < 4; nt++) {
            const floatx4 h = h_reg[mt][nt];
            po[nt] += h[0] * w0v + h[1] * w1v + h[2] * w2v + h[3] * w3v;
        }
    }
    #pragma unroll
    for (int nt = 0; nt < 4; nt++) {
        float v = po[nt];
        v += __shfl_xor(v, 16, 64);
        v += __shfl_xor(v, 32, 64);
        if (q == 0) outP[wv * 64 + nt * 16 + mi] = v;
    }
    __syncthreads();
    if (t < TILE) {
        float r = outP[t] + outP[64 + t] + outP[128 + t] + outP[192 + t] + bout[c];
        const int gi = permL[t];
        if (gi >= 0) out[gi] = r;
    }
}

extern "C" void kernel_launch(void* const* d_in, const int* in_sizes, int n_in,
                              void* d_out, int out_size, void* d_ws, size_t ws_size,
                              hipStream_t stream) {
    const float* x      = (const float*)d_in[0];
    const int*   lid    = (const int*)  d_in[1];
    const float* emb    = (const float*)d_in[2];
    const float* W0     = (const float*)d_in[3];
    const float* b0     = (const float*)d_in[4];
    const float* Wres   = (const float*)d_in[5];
    const float* bres   = (const float*)d_in[6];
    const float* scales = (const float*)d_in[7];
    const float* Wout   = (const float*)d_in[8];
    const float* bout   = (const float*)d_in[9];
    float* out = (float*)d_out;

    const int B = in_sizes[1];                          // 524288 points
    int* cnt    = (int*)d_ws;                           // [0..3]
    int* cursor = cnt + 4;                              // [4..7]
    int* perm   = cnt + 64;                             // +256 B, padded permutation (~2.1 MB)
    uint16_t* W0t = (uint16_t*)((char*)d_ws + 2228224); // +2.125 MB: [4][256][32] bf16 (64 KB)
    uint16_t* Wrt = (uint16_t*)((char*)d_ws + 2359296); // +2.25 MB: [4][3][256][256] bf16 (1.5 MB)
    uint32_t* encP = (uint32_t*)((char*)d_ws + (4u << 20));   // +4 MB: [16][B] packed bf16 pairs (32 MB)
    uint32_t* T    = (uint32_t*)((char*)d_ws + (36u << 20));  // +36 MB: bf16 pair table [16][2^19] (32 MB)
    const int nblk = B / TILE + 4;                      // 8196

    (void)hipMemsetAsync(d_ws, 0, 32, stream);
    (void)hipMemsetAsync(perm, 0xFF, (size_t)nblk * TILE * sizeof(int), stream);
    k_packtab<<<(16 * (int)HTABLE) / 256, 256, 0, stream>>>(emb, T);
    k_prep   <<<196, 256, 0, stream>>>(Wres, W0, Wrt, W0t);
    k_count  <<<B / 256, 256, 0, stream>>>(lid, B, cnt);
    k_offsets<<<1, 64, 0, stream>>>(cnt, cursor);
    k_scatter<<<B / 256, 256, 0, stream>>>(lid, B, cursor, perm);
    k_encode <<<(B / 256) * 16, 256, 0, stream>>>(x, T, encP, B);
    k_mlp2   <<<nblk, 256, 0, stream>>>(lid, encP, W0t, b0, Wrt, bres, scales, Wout, bout, perm, out, B);
}

// Round 9
// 1756.656 us; speedup vs baseline: 2.6158x; 1.1304x over previous
//
#include <hip/hip_runtime.h>
#include <stdint.h>

#define HTABLE (1u << 19)
#define TMASK  (HTABLE - 1u)
#define TILE   64
#define KSTR   264   // hB row stride in bf16 elems (528 B: 16B-aligned, 2-way-free banks)
#define KE     40    // encB row stride in bf16 elems

typedef __attribute__((ext_vector_type(8))) short short8;
typedef __attribute__((ext_vector_type(4))) float floatx4;

__device__ __forceinline__ float relu_(float v) { return fmaxf(v, 0.f); }

__device__ __forceinline__ uint32_t f2bf(float f) {
    uint32_t u = __float_as_uint(f);
    return (u + 0x7FFFu + ((u >> 16) & 1u)) >> 16;
}
__device__ __forceinline__ float bf2f(uint32_t h) { return __uint_as_float(h << 16); }

// variable-index extract from a 16B quad: 3 cndmasks, no scratch
__device__ __forceinline__ uint32_t sel4(const uint4& v, uint32_t i) {
    uint32_t lo = (i & 1u) ? v.y : v.x;
    uint32_t hi = (i & 1u) ? v.w : v.z;
    return (i & 2u) ? hi : lo;
}

__device__ __constant__ uint32_t PRS[6] = {1u, 2654435761u, 805459861u, 3674653429u, 2097192037u, 1434869437u};
__device__ __constant__ float RESF[16]  = {16.f,20.f,25.f,32.f,40.f,50.f,64.f,80.f,101.f,128.f,161.f,203.f,256.f,322.f,406.f,512.f};
__device__ __constant__ float GRIDF[16] = {1.f/16.f,1.f/20.f,1.f/25.f,1.f/32.f,1.f/40.f,1.f/50.f,1.f/64.f,1.f/80.f,
                                           1.f/101.f,1.f/128.f,1.f/161.f,1.f/203.f,1.f/256.f,1.f/322.f,1.f/406.f,1.f/512.f};

// ---------------- binning kernels ----------------
__global__ void k_count(const int* __restrict__ lid, int n, int* __restrict__ cnt) {
    __shared__ int h4[4];
    int i = blockIdx.x * blockDim.x + threadIdx.x;
    if (threadIdx.x < 4) h4[threadIdx.x] = 0;
    __syncthreads();
    if (i < n) atomicAdd(&h4[lid[i] & 3], 1);
    __syncthreads();
    if (threadIdx.x < 4) atomicAdd(&cnt[threadIdx.x], h4[threadIdx.x]);
}

__global__ void k_offsets(const int* __restrict__ cnt, int* __restrict__ cursor) {
    if (threadIdx.x == 0 && blockIdx.x == 0) {
        int off = 0;
        for (int k = 0; k < 4; k++) {
            cursor[k] = off;
            off = (off + cnt[k] + 63) & ~63;
        }
    }
}

__global__ void k_scatter(const int* __restrict__ lid, int n, int* __restrict__ cursor, int* __restrict__ perm) {
    int i = blockIdx.x * blockDim.x + threadIdx.x;
    if (i >= n) return;
    int lane = threadIdx.x & 63;
    int c = lid[i] & 3;
    unsigned long long m0 = __ballot(c == 0), m1 = __ballot(c == 1);
    unsigned long long m2 = __ballot(c == 2), m3 = __ballot(c == 3);
    unsigned long long mc = (c == 0) ? m0 : (c == 1) ? m1 : (c == 2) ? m2 : m3;
    int rank = __popcll(mc & ((1ull << lane) - 1ull));
    int cntl = (lane == 0) ? __popcll(m0) : (lane == 1) ? __popcll(m1) : (lane == 2) ? __popcll(m2) : __popcll(m3);
    int basev = 0;
    if (lane < 4) basev = atomicAdd(&cursor[lane], cntl);
    int base = __shfl(basev, c, 64);
    perm[base + rank] = i;
}

// ---------------- pack embedding table to bf16: T[l][g] = (bf16(e.x), bf16(e.y)) ----------------
__global__ __launch_bounds__(256) void k_packtab(const float* __restrict__ emb, uint32_t* __restrict__ T) {
    const int i = blockIdx.x * 256 + threadIdx.x;
    float2 e = ((const float2*)emb)[i];
    T[i] = f2bf(e.x) | (f2bf(e.y) << 16);
}

// ---------------- weight prep: transpose + bf16 ----------------
// blocks 0..191: Wres [c][ib][k][n] fp32 -> Wrt [c][ib][n][k] bf16 (64x64 tiles)
// blocks 192..195: W0 [c][32][256] fp32 -> W0t [c][256][32] bf16
__global__ __launch_bounds__(256) void k_prep(const float* __restrict__ Wres, const float* __restrict__ W0,
                                              uint16_t* __restrict__ Wrt, uint16_t* __restrict__ W0t) {
    __shared__ float sm[64 * 65 > 32 * 257 ? 64 * 65 : 32 * 257];
    const int t = threadIdx.x;
    const int bid = blockIdx.x;
    if (bid < 192) {
        const int c = bid / 48, rem = bid % 48, ib = rem / 16, tile = rem % 16;
        const int n0 = (tile / 4) * 64, k0 = (tile % 4) * 64;
        const float* src = Wres + (size_t)(c * 3 + ib) * 65536;
        for (int i = 0; i < 16; i++) {
            int idx = t + 256 * i, r = idx >> 6, cc = idx & 63;
            sm[r * 65 + cc] = src[(size_t)(k0 + r) * 256 + n0 + cc];
        }
        __syncthreads();
        uint16_t* dst = Wrt + (size_t)(c * 3 + ib) * 65536;
        for (int i = 0; i < 16; i++) {
            int idx = t + 256 * i, rn = idx >> 6, ck = idx & 63;
            dst[(size_t)(n0 + rn) * 256 + k0 + ck] = (uint16_t)f2bf(sm[ck * 65 + rn]);
        }
    } else {
        const int c = bid - 192;
        for (int i = 0; i < 32; i++) {
            int idx = t + 256 * i, k = idx >> 8, n = idx & 255;
            sm[k * 257 + n] = W0[(size_t)c * 8192 + idx];
        }
        __syncthreads();
        for (int i = 0; i < 32; i++) {
            int idx = t + 256 * i, n = idx >> 5, k = idx & 31;
            W0t[(size_t)c * 8192 + idx] = (uint16_t)f2bf(sm[k * 257 + n]);
        }
    }
}

// ---------------- encode kernel: one level per block, level -> XCD pinned ----------------
// Dim0 prime = 1 -> the dim0 vertex pair is {h, h^mask}, mask = bl0^(bl0+1).
// 3-way mask specialization (R5/R8 lesson: currency = transactions x return width):
//   mask==1 (50%): adjacent dwords -> one 8B dwordx2          (1 txn, 2 dwords)
//   mask==3 (25%): same 16B quad  -> one dwordx4 + sel4       (1 txn, 4 dwords)
//   mask>=7 (25%): two plain dword loads                      (2 txn, 2 dwords)
// Avg 40 txn / 80 return-dwords per point-level (R5: 48/64, R8: 40/160).
// Exec-masked lanes generate no transactions; h/weight math hoisted outside branches.
// REGISTER NOTE: jj-loop unroll 2 keeps in-flight loads bounded (R7 full-unroll spilled).
__global__ __launch_bounds__(256, 4) void k_encode(
    const float* __restrict__ x, const uint32_t* __restrict__ T,
    uint32_t* __restrict__ encP, int B)
{
    __shared__ float xs[256 * 6];
    const int t = threadIdx.x;
    const int NC8 = (B >> 8) << 3;
    const int pass = (blockIdx.x >= NC8) ? 1 : 0;
    const int rem  = blockIdx.x - pass * NC8;
    const int l    = (rem & 7) + (pass << 3);
    const int chunk = rem >> 3;
    const int pbase = chunk << 8;

    for (int idx = t; idx < 256 * 6; idx += 256) {
        float v = x[(size_t)pbase * 6 + idx];
        xs[idx] = fminf(fmaxf(v, 0.f), 1.f);
    }
    __syncthreads();

    const float res  = RESF[l];
    const float grid = GRIDF[l];
    float wv[6]; uint32_t ua[6], ub[6];
    #pragma unroll
    for (int d = 0; d < 6; d++) {
        float xv  = xs[t * 6 + d];
        float blf = floorf(xv * res);
        float w   = (xv - blf * grid) / (grid + 1e-6f);
        wv[d] = fminf(fmaxf(w, 0.f), 1.f);
        uint32_t uu = (uint32_t)(int)blf * PRS[d];
        ua[d] = uu; ub[d] = uu + PRS[d];
    }
    // v = (i<<4)|(j<<2)|k. Hash: dims (0,1)<-i, (2,3)<-j, (4,5)<-k (MSB-first).
    // Weights LSB-first: hash-dim0<->wv[5], dim1<->wv[4], dim2<->wv[3], dim3<->wv[2],
    // dim4<->wv[1], dim5<->wv[0] — faithful to the reference's bit-order mismatch.
    uint32_t HK[4]; float WK[4];
    #pragma unroll
    for (int q = 0; q < 4; q++) {
        const int b1 = (q >> 1) & 1, bb = q & 1;
        HK[q] = (b1 ? ub[4] : ua[4]) ^ (bb ? ub[5] : ua[5]);
        WK[q] = (bb ? wv[0] : 1.f - wv[0]) * (b1 ? wv[1] : 1.f - wv[1]);
    }
    // 8 combos of dim1 x (dims 2,3)
    uint32_t S8[8]; float W8[8];
    #pragma unroll
    for (int jj = 0; jj < 8; jj++) {
        const int j1 = jj >> 2, j = jj & 3;
        const int b1 = (j >> 1) & 1, bb = j & 1;
        const uint32_t hj = (b1 ? ub[2] : ua[2]) ^ (bb ? ub[3] : ua[3]);
        const float  wj = ((bb ? wv[2] : 1.f - wv[2]) * (b1 ? wv[3] : 1.f - wv[3]));
        S8[jj] = (j1 ? ub[1] : ua[1]) ^ hj;
        W8[jj] = (j1 ? wv[4] : 1.f - wv[4]) * wj;
    }
    const float w5a = 1.f - wv[5], w5b = wv[5];   // dim0 beta weights
    const uint32_t bl0  = ua[0];                  // prime = 1
    const uint32_t mask = bl0 ^ (bl0 + 1u);       // XOR delta of the dim0 vertex pair
    const uint32_t* __restrict__ Tl  = T + (size_t)l * HTABLE;
    const uint4*    __restrict__ Tl4 = reinterpret_cast<const uint4*>(Tl);

    float f0 = 0.f, f1 = 0.f;
    #pragma unroll 2
    for (int jj = 0; jj < 8; jj++) {
        const uint32_t Sj = S8[jj];
        const float   wj = W8[jj];
        #pragma unroll
        for (int k = 0; k < 4; k++) {
            const uint32_t h  = (bl0 ^ Sj ^ HK[k]) & TMASK;
            const float wS = wj * WK[k];
            uint32_t pa, pb;
            if (mask == 1u) {
                // adjacent dwords: one aligned 8B load serves the pair
                const uint2 pr = *(const uint2*)(Tl + (h & ~1u));
                pa = (h & 1u) ? pr.y : pr.x;
                pb = (h & 1u) ? pr.x : pr.y;
            } else if (mask == 3u) {
                // same 16B quad: one dwordx4
                const uint4 La = Tl4[h >> 2];
                const uint32_t i0 = h & 3u;
                pa = sel4(La, i0);
                pb = sel4(La, i0 ^ 3u);
            } else {
                // far pair: two plain dword loads (mask < 2^10, stays in-table)
                pa = Tl[h];
                pb = Tl[h ^ mask];
            }
            const float e0x = __uint_as_float(pa << 16),  e0y = __uint_as_float(pa & 0xFFFF0000u);
            const float e1x = __uint_as_float(pb << 16),  e1y = __uint_as_float(pb & 0xFFFF0000u);
            f0 = fmaf(wS, fmaf(w5a, e0x, w5b * e1x), f0);
            f1 = fmaf(wS, fmaf(w5a, e0y, w5b * e1y), f1);
        }
    }
    encP[(size_t)l * B + pbase + t] = f2bf(f0) | (f2bf(f1) << 16);
}

// ---------------- MFMA MLP ----------------
// Per block: 64 class-uniform points. GEMMs computed as D[n=neuron][m=point] = W^T . H
// so C/D regs (4 consecutive neurons) are k-contiguous for the next layer's B operand.
// Wave wv owns neurons [wv*64, wv*64+64); fp32 residual carry lives in h_reg.
__global__ __launch_bounds__(256, 2) void k_mlp2(
    const int* __restrict__ lid, const uint32_t* __restrict__ encP,
    const uint16_t* __restrict__ W0t, const float* __restrict__ b0,
    const uint16_t* __restrict__ Wrt, const float* __restrict__ bres,
    const float* __restrict__ scales, const float* __restrict__ Wout, const float* __restrict__ bout,
    const int* __restrict__ perm, float* __restrict__ out, int B)
{
    __shared__ uint16_t hB[64 * KSTR];     // 33792 B  H as [point][k] bf16
    __shared__ uint16_t encB[64 * KE];     //  5120 B  enc as [point][k32] bf16
    __shared__ float    bs[256];           //  per-layer bias / Wout stage
    __shared__ float    outP[256];
    __shared__ int      permL[TILE];

    const int t  = threadIdx.x;
    const int lane = t & 63;
    const int wv = t >> 6;          // wave id: neuron slice
    const int mi = lane & 15;       // point within 16-col
    const int q  = lane >> 4;       // quad

    if (t < TILE) permL[t] = perm[(size_t)blockIdx.x * TILE + t];
    __syncthreads();
    const int g0 = permL[0];
    if (g0 < 0) return;
    const int c = lid[g0] & 3;

    // stage enc [point][k=2l..2l+1] and b0
    bs[t] = b0[c * 256 + t];
    for (int idx = t; idx < 16 * 64; idx += 256) {
        const int l = idx >> 6, pp = idx & 63;
        const int gi = permL[pp];
        ((uint32_t*)encB)[pp * (KE / 2) + l] = (gi >= 0) ? encP[(size_t)l * B + gi] : 0u;
    }
    __syncthreads();

    floatx4 acc[4][4];
    floatx4 h_reg[4][4];

    // ---- layer 0: D = W0^T(256x32) . enc(32x64)
    {
        #pragma unroll
        for (int mt = 0; mt < 4; mt++)
            #pragma unroll
            for (int nt = 0; nt < 4; nt++) acc[mt][nt] = (floatx4){0.f, 0.f, 0.f, 0.f};
        const short8* Wp = (const short8*)(W0t + (size_t)c * 8192);
        short8 A[4], Bf[4];
        #pragma unroll
        for (int mt = 0; mt < 4; mt++) A[mt] = Wp[(wv * 64 + mt * 16 + mi) * 4 + q];
        #pragma unroll
        for (int nt = 0; nt < 4; nt++) Bf[nt] = *(const short8*)&encB[(nt * 16 + mi) * KE + q * 8];
        #pragma unroll
        for (int mt = 0; mt < 4; mt++)
            #pragma unroll
            for (int nt = 0; nt < 4; nt++)
                acc[mt][nt] = __builtin_amdgcn_mfma_f32_16x16x32_bf16(A[mt], Bf[nt], acc[mt][nt], 0, 0, 0);
        // h = relu(u + b0); write bf16 to hB
        #pragma unroll
        for (int mt = 0; mt < 4; mt++) {
            const int nb = wv * 64 + mt * 16 + q * 4;
            #pragma unroll
            for (int nt = 0; nt < 4; nt++) {
                floatx4 u = acc[mt][nt], h;
                h[0] = relu_(u[0] + bs[nb + 0]); h[1] = relu_(u[1] + bs[nb + 1]);
                h[2] = relu_(u[2] + bs[nb + 2]); h[3] = relu_(u[3] + bs[nb + 3]);
                h_reg[mt][nt] = h;
                uint2 pk; pk.x = f2bf(h[0]) | (f2bf(h[1]) << 16); pk.y = f2bf(h[2]) | (f2bf(h[3]) << 16);
                *(uint2*)&hB[(nt * 16 + mi) * KSTR + nb] = pk;
            }
        }
    }
    __syncthreads();

    // ---- 3 scaled residual blocks
    #pragma unroll 1
    for (int ib = 0; ib < 3; ib++) {
        bs[t] = bres[(size_t)((c * 3 + ib) << 8) + t];   // read after the post-MFMA barrier
        const float s = scales[c * 3 + ib];
        #pragma unroll
        for (int mt = 0; mt < 4; mt++)
            #pragma unroll
            for (int nt = 0; nt < 4; nt++) acc[mt][nt] = (floatx4){0.f, 0.f, 0.f, 0.f};

        const short8* Wp = (const short8*)(Wrt + (size_t)(c * 3 + ib) * 65536);
        short8 Acur[4], Anext[4], Bf[4];
        #pragma unroll
        for (int mt = 0; mt < 4; mt++) Acur[mt] = Wp[(wv * 64 + mt * 16 + mi) * 32 + q];
        #pragma unroll 1
        for (int ks = 0; ks < 8; ks++) {
            #pragma unroll
            for (int nt = 0; nt < 4; nt++)
                Bf[nt] = *(const short8*)&hB[(nt * 16 + mi) * KSTR + ks * 32 + q * 8];
            if (ks < 7) {
                #pragma unroll
                for (int mt = 0; mt < 4; mt++)
                    Anext[mt] = Wp[(wv * 64 + mt * 16 + mi) * 32 + (ks + 1) * 4 + q];
            }
            #pragma unroll
            for (int mt = 0; mt < 4; mt++)
                #pragma unroll
                for (int nt = 0; nt < 4; nt++)
                    acc[mt][nt] = __builtin_amdgcn_mfma_f32_16x16x32_bf16(Acur[mt], Bf[nt], acc[mt][nt], 0, 0, 0);
            #pragma unroll
            for (int mt = 0; mt < 4; mt++) Acur[mt] = Anext[mt];
        }
        __syncthreads();   // hB reads done; bs staged
        #pragma unroll
        for (int mt = 0; mt < 4; mt++) {
            const int nb = wv * 64 + mt * 16 + q * 4;
            #pragma unroll
            for (int nt = 0; nt < 4; nt++) {
                floatx4 u = acc[mt][nt];
                floatx4 h = h_reg[mt][nt];
                h[0] = fmaf(s, relu_(u[0] + bs[nb + 0]), h[0]);
                h[1] = fmaf(s, relu_(u[1] + bs[nb + 1]), h[1]);
                h[2] = fmaf(s, relu_(u[2] + bs[nb + 2]), h[2]);
                h[3] = fmaf(s, relu_(u[3] + bs[nb + 3]), h[3]);
                h_reg[mt][nt] = h;
                if (ib < 2) {
                    uint2 pk; pk.x = f2bf(h[0]) | (f2bf(h[1]) << 16); pk.y = f2bf(h[2]) | (f2bf(h[3]) << 16);
                    *(uint2*)&hB[(nt * 16 + mi) * KSTR + nb] = pk;
                }
            }
        }
        if (ib < 2) __syncthreads();
    }

    // ---- output layer: out[p] = sum_n h[n][p] * Wout[n] + bout
    __syncthreads();
    bs[t] = Wout[c * 256 + t];
    __syncthreads();
    float po[4] = {0.f, 0.f, 0.f, 0.f};
    #pragma unroll
    for (int mt = 0; mt < 4; mt++) {
        const int nb = wv * 64 + mt * 16 + q * 4;
        const float w0v = bs[nb + 0], w1v = bs[nb + 1], w2v = bs[nb + 2], w3v = bs[nb + 3];
        #pragma unroll
        for (int nt = 0; nt < 4; nt++) {
            const floatx4 h = h_reg[mt][nt];
            po[nt] += h[0] * w0v + h[1] * w1v + h[2] * w2v + h[3] * w3v;
        }
    }
    #pragma unroll
    for (int nt = 0; nt < 4; nt++) {
        float v = po[nt];
        v += __shfl_xor(v, 16, 64);
        v += __shfl_xor(v, 32, 64);
        if (q == 0) outP[wv * 64 + nt * 16 + mi] = v;
    }
    __syncthreads();
    if (t < TILE) {
        float r = outP[t] + outP[64 + t] + outP[128 + t] + outP[192 + t] + bout[c];
        const int gi = permL[t];
        if (gi >= 0) out[gi] = r;
    }
}

extern "C" void kernel_launch(void* const* d_in, const int* in_sizes, int n_in,
                              void* d_out, int out_size, void* d_ws, size_t ws_size,
                              hipStream_t stream) {
    const float* x      = (const float*)d_in[0];
    const int*   lid    = (const int*)  d_in[1];
    const float* emb    = (const float*)d_in[2];
    const float* W0     = (const float*)d_in[3];
    const float* b0     = (const float*)d_in[4];
    const float* Wres   = (const float*)d_in[5];
    const float* bres   = (const float*)d_in[6];
    const float* scales = (const float*)d_in[7];
    const float* Wout   = (const float*)d_in[8];
    const float* bout   = (const float*)d_in[9];
    float* out = (float*)d_out;

    const int B = in_sizes[1];                          // 524288 points
    int* cnt    = (int*)d_ws;                           // [0..3]
    int* cursor = cnt + 4;                              // [4..7]
    int* perm   = cnt + 64;                             // +256 B, padded permutation (~2.1 MB)
    uint16_t* W0t = (uint16_t*)((char*)d_ws + 2228224); // +2.125 MB: [4][256][32] bf16 (64 KB)
    uint16_t* Wrt = (uint16_t*)((char*)d_ws + 2359296); // +2.25 MB: [4][3][256][256] bf16 (1.5 MB)
    uint32_t* encP = (uint32_t*)((char*)d_ws + (4u << 20));   // +4 MB: [16][B] packed bf16 pairs (32 MB)
    uint32_t* T    = (uint32_t*)((char*)d_ws + (36u << 20));  // +36 MB: bf16 pair table [16][2^19] (32 MB)
    const int nblk = B / TILE + 4;                      // 8196

    (void)hipMemsetAsync(d_ws, 0, 32, stream);
    (void)hipMemsetAsync(perm, 0xFF, (size_t)nblk * TILE * sizeof(int), stream);
    k_packtab<<<(16 * (int)HTABLE) / 256, 256, 0, stream>>>(emb, T);
    k_prep   <<<196, 256, 0, stream>>>(Wres, W0, Wrt, W0t);
    k_count  <<<B / 256, 256, 0, stream>>>(lid, B, cnt);
    k_offsets<<<1, 64, 0, stream>>>(cnt, cursor);
    k_scatter<<<B / 256, 256, 0, stream>>>(lid, B, cursor, perm);
    k_encode <<<(B / 256) * 16, 256, 0, stream>>>(x, T, encP, B);
    k_mlp2   <<<nblk, 256, 0, stream>>>(lid, encP, W0t, b0, Wrt, bres, scales, Wout, bout, perm, out, B);
}